// Round 7
// baseline (240.898 us; speedup 1.0000x reference)
//
#include <hip/hip_runtime.h>
#include <hip/hip_bf16.h>
#include <cstdint>

typedef __bf16 bf16x8 __attribute__((ext_vector_type(8)));
typedef float f32x4 __attribute__((ext_vector_type(4)));

// ---------- helpers ----------
__device__ __forceinline__ unsigned short f2bf(float f) {
  union { float f; uint32_t u; } a; a.f = f;
  uint32_t r = a.u + 0x7fffu + ((a.u >> 16) & 1u);
  return (unsigned short)(r >> 16);
}
__device__ __forceinline__ uint32_t pk2(float lo, float hi) {
  return (uint32_t)f2bf(lo) | ((uint32_t)f2bf(hi) << 16);
}
__device__ __forceinline__ void gload_lds16(const unsigned short* g, unsigned short* l) {
  __builtin_amdgcn_global_load_lds(
      (const __attribute__((address_space(1))) void*)g,
      (__attribute__((address_space(3))) void*)l, 16, 0, 0);
}

// ---------- merged cast kernel (R4-measured version, unchanged) ----------
__global__ void cast_all(const float* __restrict__ x, const float* __restrict__ W,
                         unsigned short* __restrict__ xb, unsigned short* __restrict__ Wt) {
  __shared__ float tileW[64][65];
  const int bx = blockIdx.x;
  const int t = threadIdx.x;
  if (bx < 4096) {
    size_t i = ((size_t)bx * 256 + t) * 8;
    float4 a = *(const float4*)(x + i);
    float4 b = *(const float4*)(x + i + 4);
    uint4 o;
    o.x = pk2(a.x, a.y);
    o.y = pk2(a.z, a.w);
    o.z = pk2(b.x, b.y);
    o.w = pk2(b.z, b.w);
    *(uint4*)(xb + i) = o;
  } else {
    const int b = bx - 4096;              // 0..767
    const int z = b >> 8;                 // 0..2
    const int rest = b & 255;
    const int bxx = rest & 15, byy = rest >> 4;
    const float* Wz = W + (size_t)z * 1048576;
    unsigned short* Wtz = Wt + (size_t)z * 1048576;
    const int x0 = bxx * 64, y0 = byy * 64;
    {
      const int r = t >> 4;               // 0..15
      const int c = (t & 15) * 4;
#pragma unroll
      for (int p = 0; p < 64; p += 16) {
        float4 v = *(const float4*)(Wz + (size_t)(y0 + p + r) * 1024 + x0 + c);
        tileW[p + r][c + 0] = v.x;
        tileW[p + r][c + 1] = v.y;
        tileW[p + r][c + 2] = v.z;
        tileW[p + r][c + 3] = v.w;
      }
    }
    __syncthreads();
    {
      const int dc = (t & 7) * 8;
#pragma unroll
      for (int p = 0; p < 64; p += 32) {
        const int e = p + (t >> 3);
        uint4 o;
        o.x = pk2(tileW[dc + 0][e], tileW[dc + 1][e]);
        o.y = pk2(tileW[dc + 2][e], tileW[dc + 3][e]);
        o.z = pk2(tileW[dc + 4][e], tileW[dc + 5][e]);
        o.w = pk2(tileW[dc + 6][e], tileW[dc + 7][e]);
        *(uint4*)(Wtz + (size_t)(x0 + e) * 1024 + y0 + dc) = o;
      }
    }
  }
}

// ---------- QKV GEMM (2-phase, EXACT R4-measured codegen) ----------
// Runtime K/ldc/sA/sB/sC args deliberately kept (NOT constant-folded):
// R6 hardcoded K=1024 and the compiler's rescheduled loop ran 16% slower
// (VALUBusy 22->11.5, dur 71.5->83). This signature measured 71.5us twice.
// Tiles 128x128, BK=32, double-buffered LDS, __syncthreads per K-step,
// XOR-swizzled (SQ_LDS_BANK_CONFLICT verified 0).
// z=0 -> Q, z=1 -> K (C + z*sC); z=2 -> transposed Vt[b][e][s].
__global__ void __launch_bounds__(256)
gemm_qkv(const unsigned short* __restrict__ Aall,
         const unsigned short* __restrict__ Btall,
         unsigned short* __restrict__ QK, unsigned short* __restrict__ Vt,
         int K, int ldc, long sA, long sB, long sC) {
  __shared__ unsigned short As[2][4096];
  __shared__ unsigned short Bs[2][4096];
  const int t = threadIdx.x;
  const int lane = t & 63;
  const int quad = lane >> 4;
  const int l15 = lane & 15;
  const int wave = t >> 6;
  const int wm = (wave >> 1) * 64;
  const int wn = (wave & 1) * 64;
  const int z = blockIdx.z;

  const unsigned short* A = Aall + (size_t)z * sA + (size_t)blockIdx.x * 128 * K;
  const unsigned short* Bt = Btall + (size_t)z * sB + (size_t)blockIdx.y * 128 * K;

  const int srow = t >> 2;                             // 0..63
  const int scol = (((t & 3) ^ ((srow >> 1) & 3)) * 8);
  const unsigned short* ga = A + (size_t)srow * K + scol;
  const unsigned short* gb = Bt + (size_t)srow * K + scol;
  const size_t rowskip = (size_t)64 * K;

  const int aOff = (wm + l15) * 32 + (quad ^ ((l15 >> 1) & 3)) * 8;
  const int bOff = (wn + l15) * 32 + (quad ^ ((l15 >> 1) & 3)) * 8;

  f32x4 acc[4][4];
#pragma unroll
  for (int i = 0; i < 4; i++)
#pragma unroll
    for (int j = 0; j < 4; j++) acc[i][j] = (f32x4){0.f, 0.f, 0.f, 0.f};

  gload_lds16(ga, &As[0][t * 8]);
  gload_lds16(ga + rowskip, &As[0][2048 + t * 8]);
  gload_lds16(gb, &Bs[0][t * 8]);
  gload_lds16(gb + rowskip, &Bs[0][2048 + t * 8]);

  int buf = 0;
  for (int k0 = 0; k0 < K; k0 += 32, buf ^= 1) {
    __syncthreads();
    if (k0 + 32 < K) {
      const int kn = k0 + 32;
      gload_lds16(ga + kn, &As[buf ^ 1][t * 8]);
      gload_lds16(ga + rowskip + kn, &As[buf ^ 1][2048 + t * 8]);
      gload_lds16(gb + kn, &Bs[buf ^ 1][t * 8]);
      gload_lds16(gb + rowskip + kn, &Bs[buf ^ 1][2048 + t * 8]);
    }
    const unsigned short* aB = &As[buf][aOff];
    const unsigned short* bB = &Bs[buf][bOff];
    bf16x8 a[4], b[4];
#pragma unroll
    for (int i = 0; i < 4; i++) a[i] = *(const bf16x8*)(aB + i * 512);
#pragma unroll
    for (int j = 0; j < 4; j++) b[j] = *(const bf16x8*)(bB + j * 512);
#pragma unroll
    for (int i = 0; i < 4; i++)
#pragma unroll
      for (int j = 0; j < 4; j++)
        acc[i][j] = __builtin_amdgcn_mfma_f32_16x16x32_bf16(a[i], b[j], acc[i][j], 0, 0, 0);
  }

  // C/D layout: col = lane&15, row = quad*4 + reg  [verified m89/m91]
  const int mbase = blockIdx.x * 128 + wm + quad * 4;
  const int nbase = blockIdx.y * 128 + wn + l15;

  if (z < 2) {
    unsigned short* C = QK + (size_t)z * sC;
#pragma unroll
    for (int mi = 0; mi < 4; mi++)
#pragma unroll
      for (int ni = 0; ni < 4; ni++) {
        const int m = mbase + mi * 16, n = nbase + ni * 16;
#pragma unroll
        for (int r = 0; r < 4; r++)
          C[(size_t)(m + r) * ldc + n] = f2bf(acc[mi][ni][r]);
      }
  } else {  // z==2: Vt[b][e=n][s] <- acc, m = b*2048 + s
#pragma unroll
    for (int mi = 0; mi < 4; mi++) {
      const int m = mbase + mi * 16;
      const int b = m >> 11, s = m & 2047;
#pragma unroll
      for (int ni = 0; ni < 4; ni++) {
        const int n = nbase + ni * 16;
        uint2 val;
        val.x = pk2(acc[mi][ni][0], acc[mi][ni][1]);
        val.y = pk2(acc[mi][ni][2], acc[mi][ni][3]);
        *(uint2*)(Vt + (size_t)b * 2097152 + (size_t)n * 2048 + s) = val;
      }
    }
  }
}

#define PHASE_OPEN() do { \
    __builtin_amdgcn_sched_barrier(0); \
    __builtin_amdgcn_s_barrier(); \
    asm volatile("s_waitcnt lgkmcnt(0)" ::: "memory"); \
    __builtin_amdgcn_sched_barrier(0); \
    __builtin_amdgcn_s_setprio(1); \
  } while (0)
#define PHASE_CLOSE() do { \
    __builtin_amdgcn_s_setprio(0); \
    __builtin_amdgcn_sched_barrier(0); \
    __builtin_amdgcn_s_barrier(); \
  } while (0)

// ---------- 8-phase 256x256 GEMM: SCORES (R4-proven, unchanged) ----------
__global__ void __launch_bounds__(512, 2)
gemm8_scores(const unsigned short* __restrict__ Aall,
             const unsigned short* __restrict__ Btall,
             unsigned short* __restrict__ Call, float* __restrict__ aux,
             int K, int ldc, long sA, long sB, long sC, float scale) {
  __shared__ unsigned short As[2][2][8192];  // [dbuf][khalf][256 rows x 32]
  __shared__ unsigned short Bs[2][2][8192];
  const int t = threadIdx.x;
  const int lane = t & 63;
  const int quad = lane >> 4;
  const int l15 = lane & 15;
  const int wave = t >> 6;
  const int wm = wave >> 2;   // 0..1 : rows wm*128..+127
  const int wn = wave & 3;    // 0..3 : cols wn*64..+63
  const int z = blockIdx.z;
  const int NT = K >> 6;      // 16 for K=1024

  const unsigned short* Ab = Aall + (size_t)z * sA + (size_t)blockIdx.x * 256 * K;
  const unsigned short* Bb = Btall + (size_t)z * sB + (size_t)blockIdx.y * 256 * K;

  const int sc = (((t & 3) ^ ((t >> 3) & 3)) * 8);
  const unsigned short* gA = Ab + (size_t)(t >> 2) * K + sc;
  const unsigned short* gB = Bb + (size_t)(t >> 2) * K + sc;
  const size_t half2 = (size_t)128 * K;

  const int swz = (quad ^ ((l15 >> 1) & 3)) * 8;
  const int aRd = (wm * 128 + l15) * 32 + swz;
  const int bRd = (wn * 64 + l15) * 32 + swz;

  f32x4 acc[8][4];
#pragma unroll
  for (int i = 0; i < 8; ++i)
#pragma unroll
    for (int j = 0; j < 4; ++j) acc[i][j] = (f32x4){0.f, 0.f, 0.f, 0.f};

#define STG_A(TT, KH) do { \
    const unsigned short* g_ = gA + (TT) * 64 + (KH) * 32; \
    unsigned short* d_ = &As[(TT) & 1][KH][t * 8]; \
    gload_lds16(g_, d_); \
    gload_lds16(g_ + half2, d_ + 4096); \
  } while (0)
#define STG_B(TT, KH) do { \
    const unsigned short* g_ = gB + (TT) * 64 + (KH) * 32; \
    unsigned short* d_ = &Bs[(TT) & 1][KH][t * 8]; \
    gload_lds16(g_, d_); \
    gload_lds16(g_ + half2, d_ + 4096); \
  } while (0)

  STG_B(0, 0); STG_A(0, 0); STG_B(0, 1); STG_A(0, 1);
  STG_B(1, 0); STG_A(1, 0); STG_B(1, 1);
  asm volatile("s_waitcnt vmcnt(6)" ::: "memory");
  __builtin_amdgcn_s_barrier();

  for (int kt = 0; kt < NT; ++kt) {
    const int buf = kt & 1;
    bf16x8 bb[4], a[4];

    // ---- P1: khalf=0, row-half 0 ----
#pragma unroll
    for (int j = 0; j < 4; ++j) bb[j] = *(const bf16x8*)&Bs[buf][0][bRd + j * 512];
#pragma unroll
    for (int i = 0; i < 4; ++i) a[i] = *(const bf16x8*)&As[buf][0][aRd + i * 512];
    if (kt + 1 < NT) STG_A(kt + 1, 1);
    PHASE_OPEN();
#pragma unroll
    for (int i = 0; i < 4; ++i)
#pragma unroll
      for (int j = 0; j < 4; ++j)
        acc[i][j] = __builtin_amdgcn_mfma_f32_16x16x32_bf16(a[i], bb[j], acc[i][j], 0, 0, 0);
    PHASE_CLOSE();

    // ---- P2: khalf=0, row-half 1 (reuse bb) ----
#pragma unroll
    for (int i = 0; i < 4; ++i) a[i] = *(const bf16x8*)&As[buf][0][aRd + 2048 + i * 512];
    if (kt + 2 < NT) STG_B(kt + 2, 0);
    PHASE_OPEN();
#pragma unroll
    for (int i = 0; i < 4; ++i)
#pragma unroll
      for (int j = 0; j < 4; ++j)
        acc[4 + i][j] = __builtin_amdgcn_mfma_f32_16x16x32_bf16(a[i], bb[j], acc[4 + i][j], 0, 0, 0);
    PHASE_CLOSE();

    // ---- P3: khalf=1, row-half 0 ----
#pragma unroll
    for (int j = 0; j < 4; ++j) bb[j] = *(const bf16x8*)&Bs[buf][1][bRd + j * 512];
#pragma unroll
    for (int i = 0; i < 4; ++i) a[i] = *(const bf16x8*)&As[buf][1][aRd + i * 512];
    if (kt + 2 < NT) STG_A(kt + 2, 0);
    PHASE_OPEN();
#pragma unroll
    for (int i = 0; i < 4; ++i)
#pragma unroll
      for (int j = 0; j < 4; ++j)
        acc[i][j] = __builtin_amdgcn_mfma_f32_16x16x32_bf16(a[i], bb[j], acc[i][j], 0, 0, 0);
    PHASE_CLOSE();

    // ---- P4: khalf=1, row-half 1 (reuse bb) ----
#pragma unroll
    for (int i = 0; i < 4; ++i) a[i] = *(const bf16x8*)&As[buf][1][aRd + 2048 + i * 512];
    if (kt + 2 < NT) STG_B(kt + 2, 1);
    __builtin_amdgcn_sched_barrier(0);
    __builtin_amdgcn_s_barrier();
    asm volatile("s_waitcnt lgkmcnt(0)" ::: "memory");
    __builtin_amdgcn_sched_barrier(0);
    __builtin_amdgcn_s_setprio(1);
#pragma unroll
    for (int i = 0; i < 4; ++i)
#pragma unroll
      for (int j = 0; j < 4; ++j)
        acc[4 + i][j] = __builtin_amdgcn_mfma_f32_16x16x32_bf16(a[i], bb[j], acc[4 + i][j], 0, 0, 0);
    __builtin_amdgcn_s_setprio(0);
    __builtin_amdgcn_sched_barrier(0);
    if (kt < NT - 2) {
      asm volatile("s_waitcnt vmcnt(6)" ::: "memory");
    } else if (kt == NT - 2) {
      asm volatile("s_waitcnt vmcnt(0)" ::: "memory");
    }
    __builtin_amdgcn_s_barrier();
  }
#undef STG_A
#undef STG_B

  // epilogue: exp + store P_un + per-row partial sums
  const int mb = blockIdx.x * 256 + wm * 128 + quad * 4;
  const int nb = blockIdx.y * 256 + wn * 64 + l15;
  const int j = blockIdx.y * 4 + wn;   // 0..31
#pragma unroll
  for (int mi = 0; mi < 8; ++mi) {
#pragma unroll
    for (int r = 0; r < 4; ++r) {
      const int m = mb + mi * 16 + r;
      float s = 0.f;
#pragma unroll
      for (int ni = 0; ni < 4; ++ni) {
        const float e = __expf(acc[mi][ni][r] * scale);
        Call[(size_t)z * sC + (size_t)m * ldc + nb + ni * 16] = f2bf(e);
        s += e;
      }
      s += __shfl_xor(s, 1);
      s += __shfl_xor(s, 2);
      s += __shfl_xor(s, 4);
      s += __shfl_xor(s, 8);
      if (l15 == 0) aux[(size_t)j * 8192 + (size_t)z * 2048 + m] = s;
    }
  }
}

// ---------- 8-phase 128x256 GEMM: PV + inline rowsum reduce (R6-proven) ----------
__global__ void __launch_bounds__(512, 2)
gemm8_pv(const unsigned short* __restrict__ Aall,
         const unsigned short* __restrict__ Btall,
         float* __restrict__ Call, const float* __restrict__ partial) {
  const int K = 2048, NT = 32;
  __shared__ unsigned short As[2][2][4096];  // [dbuf][khalf][128 x 32]
  __shared__ unsigned short Bs[2][2][8192];  // [dbuf][khalf][256 x 32]
  __shared__ float lds_inv[128];
  const int t = threadIdx.x;
  const int lane = t & 63;
  const int quad = lane >> 4;
  const int l15 = lane & 15;
  const int wave = t >> 6;
  const int wm = wave >> 2;   // 0..1 : rows wm*64
  const int wn = wave & 3;    // 0..3 : cols wn*64
  const int z = blockIdx.z;

  // inline rowsum reduce (before any staging)
  if (t < 128) {
    const float* pp = partial + (size_t)z * 2048 + blockIdx.x * 128 + t;
    float s = 0.f;
#pragma unroll
    for (int j = 0; j < 32; ++j) s += pp[(size_t)j * 8192];
    lds_inv[t] = 1.f / s;
  }
  asm volatile("" ::: "memory");   // pin: reduce loads consumed before staging issues

  const unsigned short* Ab = Aall + (size_t)z * 4194304 + (size_t)blockIdx.x * 128 * K;
  const unsigned short* Bb = Btall + (size_t)z * 2097152 + (size_t)blockIdx.y * 256 * K;

  const int sc = (((t & 3) ^ ((t >> 3) & 3)) * 8);
  const unsigned short* gA = Ab + (size_t)(t >> 2) * K + sc;   // rows 0..127
  const unsigned short* gB = Bb + (size_t)(t >> 2) * K + sc;   // rows 0..127 (+bhalf)
  const size_t bhalf = (size_t)128 * K;

  const int swz = (quad ^ ((l15 >> 1) & 3)) * 8;
  const int aRd = (wm * 64 + l15) * 32 + swz;
  const int bRd = (wn * 64 + l15) * 32 + swz;

  f32x4 acc[4][4];
#pragma unroll
  for (int i = 0; i < 4; ++i)
#pragma unroll
    for (int j = 0; j < 4; ++j) acc[i][j] = (f32x4){0.f, 0.f, 0.f, 0.f};

#define STGA(TT, KH) gload_lds16(gA + (TT) * 64 + (KH) * 32, &As[(TT) & 1][KH][t * 8])
#define STGB(TT, KH) do { \
    const unsigned short* g_ = gB + (TT) * 64 + (KH) * 32; \
    unsigned short* d_ = &Bs[(TT) & 1][KH][t * 8]; \
    gload_lds16(g_, d_); \
    gload_lds16(g_ + bhalf, d_ + 4096); \
  } while (0)

  // prologue: tile0 both khalves + kh0 of tile1 (9 loads); complete tile0.
  STGB(0, 0); STGA(0, 0); STGB(0, 1); STGA(0, 1);
  STGB(1, 0); STGA(1, 0);
  asm volatile("s_waitcnt vmcnt(3)" ::: "memory");
  __builtin_amdgcn_s_barrier();

  for (int kt = 0; kt < NT; ++kt) {
    const int buf = kt & 1;
    bf16x8 bb[4], a[4];

    // ---- P1: khalf=0 ----
#pragma unroll
    for (int j = 0; j < 4; ++j) bb[j] = *(const bf16x8*)&Bs[buf][0][bRd + j * 512];
#pragma unroll
    for (int i = 0; i < 4; ++i) a[i] = *(const bf16x8*)&As[buf][0][aRd + i * 512];
    if (kt + 1 < NT) { STGB(kt + 1, 1); STGA(kt + 1, 1); }
    PHASE_OPEN();
#pragma unroll
    for (int i = 0; i < 4; ++i)
#pragma unroll
      for (int j = 0; j < 4; ++j)
        acc[i][j] = __builtin_amdgcn_mfma_f32_16x16x32_bf16(a[i], bb[j], acc[i][j], 0, 0, 0);
    PHASE_CLOSE();

    // ---- P2: khalf=1 ----
#pragma unroll
    for (int j = 0; j < 4; ++j) bb[j] = *(const bf16x8*)&Bs[buf][1][bRd + j * 512];
#pragma unroll
    for (int i = 0; i < 4; ++i) a[i] = *(const bf16x8*)&As[buf][1][aRd + i * 512];
    if (kt + 2 < NT) { STGB(kt + 2, 0); STGA(kt + 2, 0); }
    __builtin_amdgcn_sched_barrier(0);
    __builtin_amdgcn_s_barrier();
    asm volatile("s_waitcnt lgkmcnt(0)" ::: "memory");
    __builtin_amdgcn_sched_barrier(0);
    __builtin_amdgcn_s_setprio(1);
#pragma unroll
    for (int i = 0; i < 4; ++i)
#pragma unroll
      for (int j = 0; j < 4; ++j)
        acc[i][j] = __builtin_amdgcn_mfma_f32_16x16x32_bf16(a[i], bb[j], acc[i][j], 0, 0, 0);
    __builtin_amdgcn_s_setprio(0);
    __builtin_amdgcn_sched_barrier(0);
    if (kt < NT - 2) {
      asm volatile("s_waitcnt vmcnt(3)" ::: "memory");
    } else if (kt == NT - 2) {
      asm volatile("s_waitcnt vmcnt(0)" ::: "memory");
    }
    __builtin_amdgcn_s_barrier();
  }
#undef STGA
#undef STGB

  // epilogue: scale by 1/rowsum from LDS, fp32 store
  const int rb = wm * 64 + quad * 4;
  const int mb = blockIdx.x * 128 + rb;
  const int nb = blockIdx.y * 256 + wn * 64 + l15;
#pragma unroll
  for (int mi = 0; mi < 4; ++mi) {
#pragma unroll
    for (int r = 0; r < 4; ++r) {
      const int m = mb + mi * 16 + r;
      const float inv = lds_inv[rb + mi * 16 + r];
#pragma unroll
      for (int ni = 0; ni < 4; ++ni)
        Call[(size_t)z * 2097152 + (size_t)m * 1024 + nb + ni * 16] = acc[mi][ni][r] * inv;
    }
  }
}

// ---------- launcher ----------
// B=4, S=2048, D=1024. Workspace (102 MB):
//   xb @0: 16MB | Wt @16MB: 6MB (dead after QKV; partial[32][8192] overlays
//   @16MB) | Q @22MB (K = Q+8388608 elems) | Vt @54MB [4][e][s] |
//   Sb @70MB: 32MB P_unnorm bf16 [4][2048][2048]
extern "C" void kernel_launch(void* const* d_in, const int* in_sizes, int n_in,
                              void* d_out, int out_size, void* d_ws, size_t ws_size,
                              hipStream_t stream) {
  const float* x = (const float*)d_in[0];
  const float* W = (const float*)d_in[1];
  float* out = (float*)d_out;
  char* ws = (char*)d_ws;
  unsigned short* xb = (unsigned short*)(ws);
  unsigned short* Wt = (unsigned short*)(ws + (16ll << 20));
  float* partial     = (float*)(ws + (16ll << 20));   // overlays Wt after QKV
  unsigned short* Q  = (unsigned short*)(ws + (22ll << 20));
  unsigned short* Vt = (unsigned short*)(ws + (54ll << 20));
  unsigned short* Sb = (unsigned short*)(ws + (70ll << 20));

  // x fp32 -> bf16 + W transpose/cast
  cast_all<<<4864, 256, 0, stream>>>(x, W, xb, Wt);

  // merged QKV projection (2-phase, runtime-arg codegen): z=0/1 -> Q/K, z=2 -> Vt
  gemm_qkv<<<dim3(64, 8, 3), 256, 0, stream>>>(
      xb, Wt, Q, Vt, 1024, 1024, 0L, 1048576L, 8388608L);

  // P_un = exp(Q K^T / 32) (8-phase 256², grid exactly 256 blocks)
  gemm8_scores<<<dim3(8, 8, 4), 512, 0, stream>>>(
      Q, Q + 8388608, Sb, partial, 1024, 2048, 2097152L, 2097152L, 4194304L, 0.03125f);

  // out = (P_un @ V) / rowsum (8-phase 128x256, inline rowsum reduce)
  gemm8_pv<<<dim3(16, 4, 4), 512, 0, stream>>>(Sb, Vt, out, partial);
}

// Round 8
// 234.035 us; speedup vs baseline: 1.0293x; 1.0293x over previous
//
#include <hip/hip_runtime.h>
#include <hip/hip_bf16.h>
#include <cstdint>

typedef __bf16 bf16x8 __attribute__((ext_vector_type(8)));
typedef float f32x4 __attribute__((ext_vector_type(4)));

// ---------- helpers ----------
__device__ __forceinline__ unsigned short f2bf(float f) {
  union { float f; uint32_t u; } a; a.f = f;
  uint32_t r = a.u + 0x7fffu + ((a.u >> 16) & 1u);
  return (unsigned short)(r >> 16);
}
__device__ __forceinline__ uint32_t pk2(float lo, float hi) {
  return (uint32_t)f2bf(lo) | ((uint32_t)f2bf(hi) << 16);
}
__device__ __forceinline__ void gload_lds16(const unsigned short* g, unsigned short* l) {
  __builtin_amdgcn_global_load_lds(
      (const __attribute__((address_space(1))) void*)g,
      (__attribute__((address_space(3))) void*)l, 16, 0, 0);
}

// ---------- merged cast kernel (R4-measured version, unchanged) ----------
__global__ void cast_all(const float* __restrict__ x, const float* __restrict__ W,
                         unsigned short* __restrict__ xb, unsigned short* __restrict__ Wt) {
  __shared__ float tileW[64][65];
  const int bx = blockIdx.x;
  const int t = threadIdx.x;
  if (bx < 4096) {
    size_t i = ((size_t)bx * 256 + t) * 8;
    float4 a = *(const float4*)(x + i);
    float4 b = *(const float4*)(x + i + 4);
    uint4 o;
    o.x = pk2(a.x, a.y);
    o.y = pk2(a.z, a.w);
    o.z = pk2(b.x, b.y);
    o.w = pk2(b.z, b.w);
    *(uint4*)(xb + i) = o;
  } else {
    const int b = bx - 4096;              // 0..767
    const int z = b >> 8;                 // 0..2
    const int rest = b & 255;
    const int bxx = rest & 15, byy = rest >> 4;
    const float* Wz = W + (size_t)z * 1048576;
    unsigned short* Wtz = Wt + (size_t)z * 1048576;
    const int x0 = bxx * 64, y0 = byy * 64;
    {
      const int r = t >> 4;               // 0..15
      const int c = (t & 15) * 4;
#pragma unroll
      for (int p = 0; p < 64; p += 16) {
        float4 v = *(const float4*)(Wz + (size_t)(y0 + p + r) * 1024 + x0 + c);
        tileW[p + r][c + 0] = v.x;
        tileW[p + r][c + 1] = v.y;
        tileW[p + r][c + 2] = v.z;
        tileW[p + r][c + 3] = v.w;
      }
    }
    __syncthreads();
    {
      const int dc = (t & 7) * 8;
#pragma unroll
      for (int p = 0; p < 64; p += 32) {
        const int e = p + (t >> 3);
        uint4 o;
        o.x = pk2(tileW[dc + 0][e], tileW[dc + 1][e]);
        o.y = pk2(tileW[dc + 2][e], tileW[dc + 3][e]);
        o.z = pk2(tileW[dc + 4][e], tileW[dc + 5][e]);
        o.w = pk2(tileW[dc + 6][e], tileW[dc + 7][e]);
        *(uint4*)(Wtz + (size_t)(x0 + e) * 1024 + y0 + dc) = o;
      }
    }
  }
}

// ---------- QKV GEMM (2-phase, EXACT R4/R7-measured codegen: 71.5us) ----------
// Runtime K/ldc/sA/sB/sC args deliberately kept (NOT constant-folded):
// R6 hardcoded K=1024 and the compiler's rescheduled loop ran 16% slower.
// This signature measured 71.5us three times (R2/R4/R7). DO NOT TOUCH.
__global__ void __launch_bounds__(256)
gemm_qkv(const unsigned short* __restrict__ Aall,
         const unsigned short* __restrict__ Btall,
         unsigned short* __restrict__ QK, unsigned short* __restrict__ Vt,
         int K, int ldc, long sA, long sB, long sC) {
  __shared__ unsigned short As[2][4096];
  __shared__ unsigned short Bs[2][4096];
  const int t = threadIdx.x;
  const int lane = t & 63;
  const int quad = lane >> 4;
  const int l15 = lane & 15;
  const int wave = t >> 6;
  const int wm = (wave >> 1) * 64;
  const int wn = (wave & 1) * 64;
  const int z = blockIdx.z;

  const unsigned short* A = Aall + (size_t)z * sA + (size_t)blockIdx.x * 128 * K;
  const unsigned short* Bt = Btall + (size_t)z * sB + (size_t)blockIdx.y * 128 * K;

  const int srow = t >> 2;                             // 0..63
  const int scol = (((t & 3) ^ ((srow >> 1) & 3)) * 8);
  const unsigned short* ga = A + (size_t)srow * K + scol;
  const unsigned short* gb = Bt + (size_t)srow * K + scol;
  const size_t rowskip = (size_t)64 * K;

  const int aOff = (wm + l15) * 32 + (quad ^ ((l15 >> 1) & 3)) * 8;
  const int bOff = (wn + l15) * 32 + (quad ^ ((l15 >> 1) & 3)) * 8;

  f32x4 acc[4][4];
#pragma unroll
  for (int i = 0; i < 4; i++)
#pragma unroll
    for (int j = 0; j < 4; j++) acc[i][j] = (f32x4){0.f, 0.f, 0.f, 0.f};

  gload_lds16(ga, &As[0][t * 8]);
  gload_lds16(ga + rowskip, &As[0][2048 + t * 8]);
  gload_lds16(gb, &Bs[0][t * 8]);
  gload_lds16(gb + rowskip, &Bs[0][2048 + t * 8]);

  int buf = 0;
  for (int k0 = 0; k0 < K; k0 += 32, buf ^= 1) {
    __syncthreads();
    if (k0 + 32 < K) {
      const int kn = k0 + 32;
      gload_lds16(ga + kn, &As[buf ^ 1][t * 8]);
      gload_lds16(ga + rowskip + kn, &As[buf ^ 1][2048 + t * 8]);
      gload_lds16(gb + kn, &Bs[buf ^ 1][t * 8]);
      gload_lds16(gb + rowskip + kn, &Bs[buf ^ 1][2048 + t * 8]);
    }
    const unsigned short* aB = &As[buf][aOff];
    const unsigned short* bB = &Bs[buf][bOff];
    bf16x8 a[4], b[4];
#pragma unroll
    for (int i = 0; i < 4; i++) a[i] = *(const bf16x8*)(aB + i * 512);
#pragma unroll
    for (int j = 0; j < 4; j++) b[j] = *(const bf16x8*)(bB + j * 512);
#pragma unroll
    for (int i = 0; i < 4; i++)
#pragma unroll
      for (int j = 0; j < 4; j++)
        acc[i][j] = __builtin_amdgcn_mfma_f32_16x16x32_bf16(a[i], b[j], acc[i][j], 0, 0, 0);
  }

  // C/D layout: col = lane&15, row = quad*4 + reg  [verified m89/m91]
  const int mbase = blockIdx.x * 128 + wm + quad * 4;
  const int nbase = blockIdx.y * 128 + wn + l15;

  if (z < 2) {
    unsigned short* C = QK + (size_t)z * sC;
#pragma unroll
    for (int mi = 0; mi < 4; mi++)
#pragma unroll
      for (int ni = 0; ni < 4; ni++) {
        const int m = mbase + mi * 16, n = nbase + ni * 16;
#pragma unroll
        for (int r = 0; r < 4; r++)
          C[(size_t)(m + r) * ldc + n] = f2bf(acc[mi][ni][r]);
      }
  } else {  // z==2: Vt[b][e=n][s] <- acc, m = b*2048 + s
#pragma unroll
    for (int mi = 0; mi < 4; mi++) {
      const int m = mbase + mi * 16;
      const int b = m >> 11, s = m & 2047;
#pragma unroll
      for (int ni = 0; ni < 4; ni++) {
        const int n = nbase + ni * 16;
        uint2 val;
        val.x = pk2(acc[mi][ni][0], acc[mi][ni][1]);
        val.y = pk2(acc[mi][ni][2], acc[mi][ni][3]);
        *(uint2*)(Vt + (size_t)b * 2097152 + (size_t)n * 2048 + s) = val;
      }
    }
  }
}

#define PHASE_OPEN() do { \
    __builtin_amdgcn_sched_barrier(0); \
    __builtin_amdgcn_s_barrier(); \
    asm volatile("s_waitcnt lgkmcnt(0)" ::: "memory"); \
    __builtin_amdgcn_sched_barrier(0); \
    __builtin_amdgcn_s_setprio(1); \
  } while (0)
#define PHASE_CLOSE() do { \
    __builtin_amdgcn_s_setprio(0); \
    __builtin_amdgcn_sched_barrier(0); \
    __builtin_amdgcn_s_barrier(); \
  } while (0)

// ---------- 8-phase 256x256 GEMM: SCORES (R4-proven) + XCD swizzle ----------
// NEW vs R7: bijective XCD-chunked block remap. Both 8-phase kernels run at
// 1 block/CU (zero cross-block TLP), so L2-miss latency is on the critical
// path. Default dispatch round-robins 256 blocks over 8 XCDs -> each 4MB L2
// sees ALL panels. Remap l=(p%8)*32+p/8 gives each XCD a contiguous chunk of
// 32 logical blocks (8bx x 4by of one z-half): working set 8x512KB A +
// 4x512KB B = 6MB vs 32MB default.
__global__ void __launch_bounds__(512, 2)
gemm8_scores(const unsigned short* __restrict__ Aall,
             const unsigned short* __restrict__ Btall,
             unsigned short* __restrict__ Call, float* __restrict__ aux,
             int K, int ldc, long sA, long sB, long sC, float scale) {
  __shared__ unsigned short As[2][2][8192];  // [dbuf][khalf][256 rows x 32]
  __shared__ unsigned short Bs[2][2][8192];
  const int t = threadIdx.x;
  const int lane = t & 63;
  const int quad = lane >> 4;
  const int l15 = lane & 15;
  const int wave = t >> 6;
  const int wm = wave >> 2;   // 0..1 : rows wm*128..+127
  const int wn = wave & 3;    // 0..3 : cols wn*64..+63

  // XCD-chunked remap (grid 8x8x4 = 256 = 8 XCDs x 32)
  const int p_ = blockIdx.x + (blockIdx.y << 3) + (blockIdx.z << 6);
  const int l_ = ((p_ & 7) << 5) | (p_ >> 3);
  const int bxi = l_ & 7, byi = (l_ >> 3) & 7;
  const int z = l_ >> 6;
  const int NT = K >> 6;      // 16 for K=1024

  const unsigned short* Ab = Aall + (size_t)z * sA + (size_t)bxi * 256 * K;
  const unsigned short* Bb = Btall + (size_t)z * sB + (size_t)byi * 256 * K;

  const int sc = (((t & 3) ^ ((t >> 3) & 3)) * 8);
  const unsigned short* gA = Ab + (size_t)(t >> 2) * K + sc;
  const unsigned short* gB = Bb + (size_t)(t >> 2) * K + sc;
  const size_t half2 = (size_t)128 * K;

  const int swz = (quad ^ ((l15 >> 1) & 3)) * 8;
  const int aRd = (wm * 128 + l15) * 32 + swz;
  const int bRd = (wn * 64 + l15) * 32 + swz;

  f32x4 acc[8][4];
#pragma unroll
  for (int i = 0; i < 8; ++i)
#pragma unroll
    for (int j = 0; j < 4; ++j) acc[i][j] = (f32x4){0.f, 0.f, 0.f, 0.f};

#define STG_A(TT, KH) do { \
    const unsigned short* g_ = gA + (TT) * 64 + (KH) * 32; \
    unsigned short* d_ = &As[(TT) & 1][KH][t * 8]; \
    gload_lds16(g_, d_); \
    gload_lds16(g_ + half2, d_ + 4096); \
  } while (0)
#define STG_B(TT, KH) do { \
    const unsigned short* g_ = gB + (TT) * 64 + (KH) * 32; \
    unsigned short* d_ = &Bs[(TT) & 1][KH][t * 8]; \
    gload_lds16(g_, d_); \
    gload_lds16(g_ + half2, d_ + 4096); \
  } while (0)

  STG_B(0, 0); STG_A(0, 0); STG_B(0, 1); STG_A(0, 1);
  STG_B(1, 0); STG_A(1, 0); STG_B(1, 1);
  asm volatile("s_waitcnt vmcnt(6)" ::: "memory");
  __builtin_amdgcn_s_barrier();

  for (int kt = 0; kt < NT; ++kt) {
    const int buf = kt & 1;
    bf16x8 bb[4], a[4];

    // ---- P1: khalf=0, row-half 0 ----
#pragma unroll
    for (int j = 0; j < 4; ++j) bb[j] = *(const bf16x8*)&Bs[buf][0][bRd + j * 512];
#pragma unroll
    for (int i = 0; i < 4; ++i) a[i] = *(const bf16x8*)&As[buf][0][aRd + i * 512];
    if (kt + 1 < NT) STG_A(kt + 1, 1);
    PHASE_OPEN();
#pragma unroll
    for (int i = 0; i < 4; ++i)
#pragma unroll
      for (int j = 0; j < 4; ++j)
        acc[i][j] = __builtin_amdgcn_mfma_f32_16x16x32_bf16(a[i], bb[j], acc[i][j], 0, 0, 0);
    PHASE_CLOSE();

    // ---- P2: khalf=0, row-half 1 (reuse bb) ----
#pragma unroll
    for (int i = 0; i < 4; ++i) a[i] = *(const bf16x8*)&As[buf][0][aRd + 2048 + i * 512];
    if (kt + 2 < NT) STG_B(kt + 2, 0);
    PHASE_OPEN();
#pragma unroll
    for (int i = 0; i < 4; ++i)
#pragma unroll
      for (int j = 0; j < 4; ++j)
        acc[4 + i][j] = __builtin_amdgcn_mfma_f32_16x16x32_bf16(a[i], bb[j], acc[4 + i][j], 0, 0, 0);
    PHASE_CLOSE();

    // ---- P3: khalf=1, row-half 0 ----
#pragma unroll
    for (int j = 0; j < 4; ++j) bb[j] = *(const bf16x8*)&Bs[buf][1][bRd + j * 512];
#pragma unroll
    for (int i = 0; i < 4; ++i) a[i] = *(const bf16x8*)&As[buf][1][aRd + i * 512];
    if (kt + 2 < NT) STG_A(kt + 2, 0);
    PHASE_OPEN();
#pragma unroll
    for (int i = 0; i < 4; ++i)
#pragma unroll
      for (int j = 0; j < 4; ++j)
        acc[i][j] = __builtin_amdgcn_mfma_f32_16x16x32_bf16(a[i], bb[j], acc[i][j], 0, 0, 0);
    PHASE_CLOSE();

    // ---- P4: khalf=1, row-half 1 (reuse bb) ----
#pragma unroll
    for (int i = 0; i < 4; ++i) a[i] = *(const bf16x8*)&As[buf][1][aRd + 2048 + i * 512];
    if (kt + 2 < NT) STG_B(kt + 2, 1);
    __builtin_amdgcn_sched_barrier(0);
    __builtin_amdgcn_s_barrier();
    asm volatile("s_waitcnt lgkmcnt(0)" ::: "memory");
    __builtin_amdgcn_sched_barrier(0);
    __builtin_amdgcn_s_setprio(1);
#pragma unroll
    for (int i = 0; i < 4; ++i)
#pragma unroll
      for (int j = 0; j < 4; ++j)
        acc[4 + i][j] = __builtin_amdgcn_mfma_f32_16x16x32_bf16(a[i], bb[j], acc[4 + i][j], 0, 0, 0);
    __builtin_amdgcn_s_setprio(0);
    __builtin_amdgcn_sched_barrier(0);
    if (kt < NT - 2) {
      asm volatile("s_waitcnt vmcnt(6)" ::: "memory");
    } else if (kt == NT - 2) {
      asm volatile("s_waitcnt vmcnt(0)" ::: "memory");
    }
    __builtin_amdgcn_s_barrier();
  }
#undef STG_A
#undef STG_B

  // epilogue: exp + store P_un + per-row partial sums
  const int mb = bxi * 256 + wm * 128 + quad * 4;
  const int nb = byi * 256 + wn * 64 + l15;
  const int j = byi * 4 + wn;   // 0..31
#pragma unroll
  for (int mi = 0; mi < 8; ++mi) {
#pragma unroll
    for (int r = 0; r < 4; ++r) {
      const int m = mb + mi * 16 + r;
      float s = 0.f;
#pragma unroll
      for (int ni = 0; ni < 4; ++ni) {
        const float e = __expf(acc[mi][ni][r] * scale);
        Call[(size_t)z * sC + (size_t)m * ldc + nb + ni * 16] = f2bf(e);
        s += e;
      }
      s += __shfl_xor(s, 1);
      s += __shfl_xor(s, 2);
      s += __shfl_xor(s, 4);
      s += __shfl_xor(s, 8);
      if (l15 == 0) aux[(size_t)j * 8192 + (size_t)z * 2048 + m] = s;
    }
  }
}

// ---------- 8-phase 128x256 GEMM: PV + inline reduce + XCD swizzle ----------
// Remap with by-fastest decode: each XCD chunk of 32 = {by 0..3 (all), bx
// 0..7} of one z -> full A-panel reuse (4 by-blocks per A-panel co-located);
// working set 8x512KB A + 4x1MB B = 8MB vs 48MB default.
__global__ void __launch_bounds__(512, 2)
gemm8_pv(const unsigned short* __restrict__ Aall,
         const unsigned short* __restrict__ Btall,
         float* __restrict__ Call, const float* __restrict__ partial) {
  const int K = 2048, NT = 32;
  __shared__ unsigned short As[2][2][4096];  // [dbuf][khalf][128 x 32]
  __shared__ unsigned short Bs[2][2][8192];  // [dbuf][khalf][256 x 32]
  __shared__ float lds_inv[128];
  const int t = threadIdx.x;
  const int lane = t & 63;
  const int quad = lane >> 4;
  const int l15 = lane & 15;
  const int wave = t >> 6;
  const int wm = wave >> 2;   // 0..1 : rows wm*64
  const int wn = wave & 3;    // 0..3 : cols wn*64

  // XCD-chunked remap (grid 16x4x4 = 256 = 8 XCDs x 32), by-fastest decode
  const int p_ = blockIdx.x + (blockIdx.y << 4) + (blockIdx.z << 6);
  const int l_ = ((p_ & 7) << 5) | (p_ >> 3);
  const int byi = l_ & 3, bxi = (l_ >> 2) & 15;
  const int z = l_ >> 6;

  // inline rowsum reduce (before any staging)
  if (t < 128) {
    const float* pp = partial + (size_t)z * 2048 + bxi * 128 + t;
    float s = 0.f;
#pragma unroll
    for (int j = 0; j < 32; ++j) s += pp[(size_t)j * 8192];
    lds_inv[t] = 1.f / s;
  }
  asm volatile("" ::: "memory");   // pin: reduce loads consumed before staging issues

  const unsigned short* Ab = Aall + (size_t)z * 4194304 + (size_t)bxi * 128 * K;
  const unsigned short* Bb = Btall + (size_t)z * 2097152 + (size_t)byi * 256 * K;

  const int sc = (((t & 3) ^ ((t >> 3) & 3)) * 8);
  const unsigned short* gA = Ab + (size_t)(t >> 2) * K + sc;   // rows 0..127
  const unsigned short* gB = Bb + (size_t)(t >> 2) * K + sc;   // rows 0..127 (+bhalf)
  const size_t bhalf = (size_t)128 * K;

  const int swz = (quad ^ ((l15 >> 1) & 3)) * 8;
  const int aRd = (wm * 64 + l15) * 32 + swz;
  const int bRd = (wn * 64 + l15) * 32 + swz;

  f32x4 acc[4][4];
#pragma unroll
  for (int i = 0; i < 4; ++i)
#pragma unroll
    for (int j = 0; j < 4; ++j) acc[i][j] = (f32x4){0.f, 0.f, 0.f, 0.f};

#define STGA(TT, KH) gload_lds16(gA + (TT) * 64 + (KH) * 32, &As[(TT) & 1][KH][t * 8])
#define STGB(TT, KH) do { \
    const unsigned short* g_ = gB + (TT) * 64 + (KH) * 32; \
    unsigned short* d_ = &Bs[(TT) & 1][KH][t * 8]; \
    gload_lds16(g_, d_); \
    gload_lds16(g_ + bhalf, d_ + 4096); \
  } while (0)

  // prologue: tile0 both khalves + kh0 of tile1 (9 loads); complete tile0.
  STGB(0, 0); STGA(0, 0); STGB(0, 1); STGA(0, 1);
  STGB(1, 0); STGA(1, 0);
  asm volatile("s_waitcnt vmcnt(3)" ::: "memory");
  __builtin_amdgcn_s_barrier();

  for (int kt = 0; kt < NT; ++kt) {
    const int buf = kt & 1;
    bf16x8 bb[4], a[4];

    // ---- P1: khalf=0 ----
#pragma unroll
    for (int j = 0; j < 4; ++j) bb[j] = *(const bf16x8*)&Bs[buf][0][bRd + j * 512];
#pragma unroll
    for (int i = 0; i < 4; ++i) a[i] = *(const bf16x8*)&As[buf][0][aRd + i * 512];
    if (kt + 1 < NT) { STGB(kt + 1, 1); STGA(kt + 1, 1); }
    PHASE_OPEN();
#pragma unroll
    for (int i = 0; i < 4; ++i)
#pragma unroll
      for (int j = 0; j < 4; ++j)
        acc[i][j] = __builtin_amdgcn_mfma_f32_16x16x32_bf16(a[i], bb[j], acc[i][j], 0, 0, 0);
    PHASE_CLOSE();

    // ---- P2: khalf=1 ----
#pragma unroll
    for (int j = 0; j < 4; ++j) bb[j] = *(const bf16x8*)&Bs[buf][1][bRd + j * 512];
#pragma unroll
    for (int i = 0; i < 4; ++i) a[i] = *(const bf16x8*)&As[buf][1][aRd + i * 512];
    if (kt + 2 < NT) { STGB(kt + 2, 0); STGA(kt + 2, 0); }
    __builtin_amdgcn_sched_barrier(0);
    __builtin_amdgcn_s_barrier();
    asm volatile("s_waitcnt lgkmcnt(0)" ::: "memory");
    __builtin_amdgcn_sched_barrier(0);
    __builtin_amdgcn_s_setprio(1);
#pragma unroll
    for (int i = 0; i < 4; ++i)
#pragma unroll
      for (int j = 0; j < 4; ++j)
        acc[i][j] = __builtin_amdgcn_mfma_f32_16x16x32_bf16(a[i], bb[j], acc[i][j], 0, 0, 0);
    __builtin_amdgcn_s_setprio(0);
    __builtin_amdgcn_sched_barrier(0);
    if (kt < NT - 2) {
      asm volatile("s_waitcnt vmcnt(3)" ::: "memory");
    } else if (kt == NT - 2) {
      asm volatile("s_waitcnt vmcnt(0)" ::: "memory");
    }
    __builtin_amdgcn_s_barrier();
  }
#undef STGA
#undef STGB

  // epilogue: scale by 1/rowsum from LDS, fp32 store
  const int rb = wm * 64 + quad * 4;
  const int mb = bxi * 128 + rb;
  const int nb = byi * 256 + wn * 64 + l15;
#pragma unroll
  for (int mi = 0; mi < 4; ++mi) {
#pragma unroll
    for (int r = 0; r < 4; ++r) {
      const int m = mb + mi * 16 + r;
      const float inv = lds_inv[rb + mi * 16 + r];
#pragma unroll
      for (int ni = 0; ni < 4; ++ni)
        Call[(size_t)z * 2097152 + (size_t)m * 1024 + nb + ni * 16] = acc[mi][ni][r] * inv;
    }
  }
}

// ---------- launcher ----------
// B=4, S=2048, D=1024. Workspace (102 MB):
//   xb @0: 16MB | Wt @16MB: 6MB (dead after QKV; partial[32][8192] overlays
//   @16MB) | Q @22MB (K = Q+8388608 elems) | Vt @54MB [4][e][s] |
//   Sb @70MB: 32MB P_unnorm bf16 [4][2048][2048]
extern "C" void kernel_launch(void* const* d_in, const int* in_sizes, int n_in,
                              void* d_out, int out_size, void* d_ws, size_t ws_size,
                              hipStream_t stream) {
  const float* x = (const float*)d_in[0];
  const float* W = (const float*)d_in[1];
  float* out = (float*)d_out;
  char* ws = (char*)d_ws;
  unsigned short* xb = (unsigned short*)(ws);
  unsigned short* Wt = (unsigned short*)(ws + (16ll << 20));
  float* partial     = (float*)(ws + (16ll << 20));   // overlays Wt after QKV
  unsigned short* Q  = (unsigned short*)(ws + (22ll << 20));
  unsigned short* Vt = (unsigned short*)(ws + (54ll << 20));
  unsigned short* Sb = (unsigned short*)(ws + (70ll << 20));

  // x fp32 -> bf16 + W transpose/cast
  cast_all<<<4864, 256, 0, stream>>>(x, W, xb, Wt);

  // merged QKV projection (2-phase, runtime-arg codegen): z=0/1 -> Q/K, z=2 -> Vt
  gemm_qkv<<<dim3(64, 8, 3), 256, 0, stream>>>(
      xb, Wt, Q, Vt, 1024, 1024, 0L, 1048576L, 8388608L);

  // P_un = exp(Q K^T / 32) (8-phase 256², XCD-swizzled, 256 blocks)
  gemm8_scores<<<dim3(8, 8, 4), 512, 0, stream>>>(
      Q, Q + 8388608, Sb, partial, 1024, 2048, 2097152L, 2097152L, 4194304L, 0.03125f);

  // out = (P_un @ V) / rowsum (8-phase 128x256, XCD-swizzled, inline reduce)
  gemm8_pv<<<dim3(16, 4, 4), 512, 0, stream>>>(Sb, Vt, out, partial);
}